// Round 3
// baseline (325.258 us; speedup 1.0000x reference)
//
#include <hip/hip_runtime.h>

// GCN3 round 9: pipeline collapse. 9 -> 6 dispatches.
//  - k_place now also converts+prescales x (xscale fused; dis from LDS).
//  - k_fused1 = aggL1 + gemm1 + gemm2 in one kernel: W1+W2 whole in LDS
//    (128KB) + swizzled 16KB xa tile (144KB total, 1 block/CU, 512 thr).
//    xa never hits global; h1 written fp32 (output) and re-read block-hot
//    for gemm2's A (cross-wave, so after __syncthreads vmcnt drain).
//  - aggL2 / agg1d unchanged from round 8.

typedef __attribute__((ext_vector_type(8))) short short8;   // 8 bf16 (4 VGPR)
typedef __attribute__((ext_vector_type(4))) float f32x4;    // MFMA C/D

static __device__ __forceinline__ unsigned short f2bf(float f){
  union { float f; unsigned u; } v; v.f = f;
  unsigned r = v.u + 0x7FFF + ((v.u >> 16) & 1);            // RNE
  return (unsigned short)(r >> 16);
}
static __device__ __forceinline__ float2 bf2f2(unsigned u){
  union { unsigned u; float f; } a, b;
  a.u = u << 16; b.u = u & 0xffff0000u;
  return make_float2(a.f, b.f);
}

// ---------------- fused: edge binning + W frag-pack ----------------
__global__ __launch_bounds__(256) void k_prepbin(
    const int* __restrict__ src, const int* __restrict__ dst,
    int* __restrict__ bcur, unsigned* __restrict__ pairs, int E, int binB,
    const float* __restrict__ W1, const float* __restrict__ W2,
    unsigned short* __restrict__ Wf1, unsigned short* __restrict__ Wf2){
  __shared__ int cl[256];
  int blk = blockIdx.x;
  int tid = threadIdx.x;
  if (blk < binB){
    int e0 = blk * 4096 + tid;
    cl[tid] = 0; __syncthreads();
    #pragma unroll
    for (int i = 0; i < 16; i++){
      int e = e0 + i*256;
      if (e < E) atomicAdd(&cl[dst[e] >> 8], 1);
    }
    __syncthreads();
    int c = cl[tid];
    int g = (c > 0) ? atomicAdd(&bcur[tid], c) : 0;   // reserve contiguous run
    cl[tid] = g;
    __syncthreads();
    #pragma unroll
    for (int i = 0; i < 16; i++){
      int e = e0 + i*256;
      if (e < E){
        int d = dst[e];
        int b = d >> 8;
        int p = atomicAdd(&cl[b], 1);
        pairs[(b << 13) + p] = (unsigned)src[e] | ((unsigned)(d & 255) << 16);
      }
    }
  } else {
    int t = (blk - binB)*256 + tid;                   // 65536 pack threads
    if (t < 32768){
      // Wf1 [16 nt][4 kt][64 lane][8 j] from W1[128][256]
      int j = t & 7, lane = (t>>3) & 63, kt = (t>>9) & 3, nt = t >> 11;
      int nn = nt*16 + (lane & 15);
      int kk = kt*32 + (lane>>4)*8 + j;
      Wf1[t] = f2bf(W1[kk*256 + nn]);
    } else {
      // Wf2 [2 h][8 kt][4 ntl][64 lane][8 j] from W2[256][128]; nt = h*4+ntl
      int o = t - 32768;
      int j = o & 7, lane = (o>>3) & 63, ntl = (o>>9) & 3, kt = (o>>11) & 7, h = o >> 14;
      int nn = (h*4 + ntl)*16 + (lane & 15);
      int kk = kt*32 + (lane>>4)*8 + j;
      Wf2[o] = f2bf(W2[kk*128 + nn]);
    }
  }
}

// one block per bucket: node histogram + scans -> rowptr/cnt/dis + csr scatter
// + fused x -> bf16 prescale (xbs = bf16(dis*x)) for this block's 256 nodes
__global__ __launch_bounds__(256) void k_place(
    const int* __restrict__ bcur, const unsigned* __restrict__ pairs,
    unsigned short* __restrict__ csr_src, int* __restrict__ rowptr,
    int* __restrict__ cnt, float* __restrict__ dis,
    const float4* __restrict__ x, uint2* __restrict__ xbs,
    int n, int nb){
  __shared__ int sh[256];
  __shared__ int ncnt[256];
  __shared__ float disl[256];
  int t = threadIdx.x;
  int b = blockIdx.x;
  int v = (t < nb) ? bcur[t] : 0;
  sh[t] = v; __syncthreads();
  for (int off = 1; off < 256; off <<= 1){
    int xx = (t >= off) ? sh[t-off] : 0;
    __syncthreads(); sh[t] += xx; __syncthreads();
  }
  int csr_base = (b == 0) ? 0 : sh[b-1];
  int cnt_b = bcur[b];
  ncnt[t] = 0; __syncthreads();
  const unsigned* P = pairs + ((size_t)b << 13);
  for (int i = t; i < cnt_b; i += 256) atomicAdd(&ncnt[P[i] >> 16], 1);
  __syncthreads();
  int c = ncnt[t];
  sh[t] = c; __syncthreads();
  for (int off = 1; off < 256; off <<= 1){
    int xx = (t >= off) ? sh[t-off] : 0;
    __syncthreads(); sh[t] += xx; __syncthreads();
  }
  int noff = sh[t] - c;
  int node = (b << 8) + t;
  float di = rsqrtf((float)(c + 1));
  disl[t] = di;
  if (node < n){
    rowptr[node] = csr_base + noff;
    cnt[node] = c;
    dis[node] = di;                               // +1 self loop
  }
  ncnt[t] = noff; __syncthreads();
  for (int i = t; i < cnt_b; i += 256){
    unsigned u = P[i];
    int p = atomicAdd(&ncnt[u >> 16], 1);
    csr_src[csr_base + p] = (unsigned short)(u & 0xffff);
  }
  // fused xscale: this block's 256 nodes = float4 range [b*8192, b*8192+8192)
  const float4* xg = x + (size_t)b*8192;
  uint2* xo = xbs + (size_t)b*8192;
  int lim = n*32 - b*8192;
  for (int i = t; i < 8192 && i < lim; i += 256){
    float d = disl[i >> 5];
    float4 vv = xg[i];
    xo[i] = make_uint2((unsigned)f2bf(d*vv.x) | ((unsigned)f2bf(d*vv.y) << 16),
                       (unsigned)f2bf(d*vv.z) | ((unsigned)f2bf(d*vv.w) << 16));
  }
}

// ---------------- fused: aggL1 -> GEMM1 -> GEMM2, 64 rows per block ----------------
// LDS: W1 frags (64KB) + W2 frags (64KB) + xa tile (16KB, XOR-swizzled) = 144KB
__global__ __launch_bounds__(512) void k_fused1(
    const unsigned* __restrict__ xbs,
    const int* __restrict__ rowptr, const int* __restrict__ cnt,
    const unsigned short* __restrict__ csr_src,
    const float* __restrict__ dis,
    const unsigned short* __restrict__ Wf1, const unsigned short* __restrict__ Wf2,
    const float* __restrict__ b1,
    float* __restrict__ h1, unsigned short* __restrict__ T2s, int n)
{
  __shared__ unsigned short W1l[32768];   // 64 KB
  __shared__ unsigned short W2l[32768];   // 64 KB
  __shared__ unsigned short xal[8192];    // 16 KB: [64 rows][128 bf16], swizzled
  int t = threadIdx.x;
  int w = t >> 6, lane = t & 63;
  int row0 = blockIdx.x * 64;

  // ---- stage W1+W2 (128 KB, L2-hot) ----
  {
    const float4* s1 = (const float4*)Wf1;  float4* d1 = (float4*)W1l;
    const float4* s2 = (const float4*)Wf2;  float4* d2 = (float4*)W2l;
    #pragma unroll
    for (int i = 0; i < 8; i++) d1[i*512 + t] = s1[i*512 + t];
    #pragma unroll
    for (int i = 0; i < 8; i++) d2[i*512 + t] = s2[i*512 + t];
  }

  // ---- gather-aggregate: wave w owns block-local nodes w*8 .. w*8+7 ----
  for (int k = 0; k < 8; k++){
    int nloc = w*8 + k;
    int node = row0 + nloc;
    float2 acc = make_float2(0.f, 0.f);
    if (node < n){
      acc = bf2f2(xbs[(size_t)node*64 + lane]);       // self term (prescaled)
      int start = rowptr[node];
      int mm = cnt[node];
      int j = 0;
      for (; j + 15 < mm; j += 16){
        int s[16]; unsigned uv[16];
        #pragma unroll
        for (int q = 0; q < 16; q++) s[q] = csr_src[start+j+q];
        #pragma unroll
        for (int q = 0; q < 16; q++) uv[q] = xbs[(size_t)s[q]*64 + lane];
        #pragma unroll
        for (int q = 0; q < 16; q++){
          float2 u = bf2f2(uv[q]);
          acc.x += u.x; acc.y += u.y;
        }
      }
      for (; j + 3 < mm; j += 4){
        int s[4]; unsigned uv[4];
        #pragma unroll
        for (int q = 0; q < 4; q++) s[q] = csr_src[start+j+q];
        #pragma unroll
        for (int q = 0; q < 4; q++) uv[q] = xbs[(size_t)s[q]*64 + lane];
        #pragma unroll
        for (int q = 0; q < 4; q++){
          float2 u = bf2f2(uv[q]);
          acc.x += u.x; acc.y += u.y;
        }
      }
      for (; j < mm; j++){
        float2 u = bf2f2(xbs[(size_t)csr_src[start+j]*64 + lane]);
        acc.x += u.x; acc.y += u.y;
      }
      float di = dis[node];
      acc.x *= di; acc.y *= di;
    }
    unsigned off = (unsigned)(lane*4) ^ ((unsigned)(nloc & 7) << 4);  // T2 swizzle
    *(unsigned*)((char*)xal + nloc*256 + off) =
        (unsigned)f2bf(acc.x) | ((unsigned)f2bf(acc.y) << 16);
  }
  __syncthreads();

  // ---- GEMM1: xa[64][128] @ W1 -> h1[64][256] (+b1, relu) ----
  int m = lane & 15, q = lane >> 4;
  int stripe = w & 3;              // 16-row stripe
  int nth = w >> 2;                // col half (0: cols 0-127, 1: 128-255)
  short8 af[4];
  {
    int rl = stripe*16 + m;
    #pragma unroll
    for (int kt = 0; kt < 4; kt++){
      unsigned off = (unsigned)(kt*64 + q*16) ^ ((unsigned)(rl & 7) << 4);
      af[kt] = *(const short8*)((const char*)xal + rl*256 + off);
    }
  }
  f32x4 acc1[8];
  #pragma unroll
  for (int i = 0; i < 8; i++) acc1[i] = (f32x4){0.f,0.f,0.f,0.f};
  const short8* Wv1 = (const short8*)W1l;
  #pragma unroll
  for (int nt = 0; nt < 8; nt++){
    int ntg = nth*8 + nt;
    #pragma unroll
    for (int kt = 0; kt < 4; kt++){
      short8 bfr = Wv1[(ntg*4 + kt)*64 + lane];
      acc1[nt] = __builtin_amdgcn_mfma_f32_16x16x32_bf16(af[kt], bfr, acc1[nt], 0, 0, 0);
    }
  }
  int rowa = row0 + stripe*16 + q*4;
  #pragma unroll
  for (int nt = 0; nt < 8; nt++){
    int col = nth*128 + nt*16 + m;
    float b = b1[col];
    #pragma unroll
    for (int r = 0; r < 4; r++){
      int rr = rowa + r;
      if (rr < n)
        h1[(size_t)rr*256 + col] = fmaxf(acc1[nt][r] + b, 0.0f);
    }
  }
  __syncthreads();   // drains vmcnt -> h1 visible block-wide (L1/L2 hot)

  // ---- GEMM2: h1[64][256] (reload, ->bf16) @ W2 -> t2s[64][128] (dis-prescaled) ----
  short8 af2[8];
  {
    int rowm = row0 + stripe*16 + m;
    int ra = (rowm < n) ? rowm : (n-1);
    const float4* A2 = (const float4*)(h1 + (size_t)ra*256);
    #pragma unroll
    for (int kt = 0; kt < 8; kt++){
      float4 a0 = A2[kt*8 + q*2];
      float4 a1 = A2[kt*8 + q*2 + 1];
      short8 vv;
      vv[0] = (short)f2bf(a0.x); vv[1] = (short)f2bf(a0.y);
      vv[2] = (short)f2bf(a0.z); vv[3] = (short)f2bf(a0.w);
      vv[4] = (short)f2bf(a1.x); vv[5] = (short)f2bf(a1.y);
      vv[6] = (short)f2bf(a1.z); vv[7] = (short)f2bf(a1.w);
      af2[kt] = vv;
    }
  }
  f32x4 acc2[4];
  #pragma unroll
  for (int i = 0; i < 4; i++) acc2[i] = (f32x4){0.f,0.f,0.f,0.f};
  const short8* Wv2 = (const short8*)W2l;
  #pragma unroll
  for (int nt = 0; nt < 4; nt++){
    #pragma unroll
    for (int kt = 0; kt < 8; kt++){
      short8 bfr = Wv2[((nth*8 + kt)*4 + nt)*64 + lane];
      acc2[nt] = __builtin_amdgcn_mfma_f32_16x16x32_bf16(af2[kt], bfr, acc2[nt], 0, 0, 0);
    }
  }
  float dsv[4];
  #pragma unroll
  for (int r = 0; r < 4; r++){
    int rr = rowa + r;
    dsv[r] = (rr < n) ? dis[rr] : 0.0f;
  }
  #pragma unroll
  for (int nt = 0; nt < 4; nt++){
    int col = nth*64 + nt*16 + m;
    #pragma unroll
    for (int r = 0; r < 4; r++){
      int rr = rowa + r;
      if (rr < n) T2s[(size_t)rr*128 + col] = f2bf(dsv[r] * acc2[nt][r]);
    }
  }
}

// ---------------- aggregation L2: prescaled gather -> h2 fp32 (+b2,relu) + us=dis*(h2.W3) ----------------
__global__ void k_aggL2(const unsigned* __restrict__ t2s, float* __restrict__ h2,
                        const int* __restrict__ rowptr, const int* __restrict__ cnt,
                        const unsigned short* __restrict__ csr_src,
                        const float* __restrict__ dis,
                        const float* __restrict__ b2, const float* __restrict__ W3,
                        float* __restrict__ u, int n){
  int t = threadIdx.x;
  int lane = t & 63;
  int node = blockIdx.x*4 + (t >> 6);
  if (node >= n) return;
  float di = dis[node];
  float2 acc = bf2f2(t2s[(size_t)node*64 + lane]);   // self term (prescaled)
  int start = rowptr[node];
  int mm = cnt[node];
  int j = 0;
  for (; j + 15 < mm; j += 16){
    int s[16]; unsigned uv[16];
    #pragma unroll
    for (int q = 0; q < 16; q++) s[q] = csr_src[start+j+q];
    #pragma unroll
    for (int q = 0; q < 16; q++) uv[q] = t2s[(size_t)s[q]*64 + lane];
    #pragma unroll
    for (int q = 0; q < 16; q++){
      float2 uu = bf2f2(uv[q]);
      acc.x += uu.x; acc.y += uu.y;
    }
  }
  for (; j + 3 < mm; j += 4){
    int s[4]; unsigned uv[4];
    #pragma unroll
    for (int q = 0; q < 4; q++) s[q] = csr_src[start+j+q];
    #pragma unroll
    for (int q = 0; q < 4; q++) uv[q] = t2s[(size_t)s[q]*64 + lane];
    #pragma unroll
    for (int q = 0; q < 4; q++){
      float2 uu = bf2f2(uv[q]);
      acc.x += uu.x; acc.y += uu.y;
    }
  }
  for (; j < mm; j++){
    float2 uu = bf2f2(t2s[(size_t)csr_src[start+j]*64 + lane]);
    acc.x += uu.x; acc.y += uu.y;
  }
  float2 b = ((const float2*)b2)[lane];
  acc.x = fmaxf(fmaf(di, acc.x, b.x), 0.0f);
  acc.y = fmaxf(fmaf(di, acc.y, b.y), 0.0f);
  ((float2*)h2)[(size_t)node*64 + lane] = acc;
  float up = fmaf(acc.x, W3[2*lane], acc.y * W3[2*lane+1]);
  #pragma unroll
  for (int off = 32; off > 0; off >>= 1) up += __shfl_down(up, off);
  if (lane == 0) u[node] = di * up;               // pre-scaled for final agg
}

// ---------------- final scalar aggregation: 16 lanes per node ----------------
__global__ void k_agg1d(const float* __restrict__ us, float* __restrict__ y,
                        const int* __restrict__ rowptr, const int* __restrict__ cnt,
                        const unsigned short* __restrict__ csr_src,
                        const float* __restrict__ dis,
                        const float* __restrict__ b3, int n){
  int t = threadIdx.x;
  int node = blockIdx.x*16 + (t >> 4);
  int sub = t & 15;
  if (node >= n) return;
  int s0 = rowptr[node];
  int m = cnt[node];
  float acc = (sub == 0) ? us[node] : 0.0f;        // self (prescaled)
  for (int j = sub; j < m; j += 16)
    acc += us[csr_src[s0 + j]];
  #pragma unroll
  for (int off = 8; off > 0; off >>= 1) acc += __shfl_xor(acc, off);
  if (sub == 0) y[node] = fmaf(dis[node], acc, b3[0]);
}

extern "C" void kernel_launch(void* const* d_in, const int* in_sizes, int n_in,
                              void* d_out, int out_size, void* d_ws, size_t ws_size,
                              hipStream_t stream){
  const float* x  = (const float*)d_in[0];
  const int*  ei  = (const int*)d_in[1];
  const float* W1 = (const float*)d_in[2];
  const float* b1 = (const float*)d_in[3];
  const float* W2 = (const float*)d_in[4];
  const float* b2 = (const float*)d_in[5];
  const float* W3 = (const float*)d_in[6];
  const float* b3 = (const float*)d_in[7];
  const int N = in_sizes[0] / 128;
  const int E = in_sizes[1] / 2;
  const int* src = ei;
  const int* dst = ei + E;
  const int NB = (N + 255) >> 8;      // 196 buckets

  char* p = (char*)d_ws;
  auto alloc = [&](size_t bytes)->char*{
    char* r = p; p += (bytes + 255) & ~(size_t)255; return r;
  };
  int*   bcur    = (int*)  alloc(256*4);
  int*   rowptr  = (int*)  alloc((size_t)N*4);
  int*   cnt     = (int*)  alloc((size_t)N*4);
  float* dis     = (float*)alloc((size_t)N*4);
  unsigned* pairs = (unsigned*)alloc((size_t)NB*8192*4);
  unsigned short* csr_src = (unsigned short*)alloc((size_t)E*2);
  unsigned* xbs  = (unsigned*)alloc((size_t)N*128*2);   // bf16 dis*x
  unsigned short* t2s = (unsigned short*)alloc((size_t)N*128*2); // bf16 dis*(h1@W2)
  float* u       = (float*)alloc((size_t)N*4);          // dis*(h2@W3)
  unsigned short* wf1 = (unsigned short*)alloc(32768*2);
  unsigned short* wf2 = (unsigned short*)alloc(32768*2);

  float* y  = (float*)d_out;
  float* h1 = y + N;
  float* h2 = h1 + (size_t)N*256;

  int bb = (E + 4095)/4096;           // 196 bin blocks

  hipMemsetAsync(bcur, 0, 256*4, stream);
  k_prepbin <<<bb + 256, 256, 0, stream>>>(
      src, dst, bcur, pairs, E, bb, W1, W2, wf1, wf2);
  k_place   <<<NB, 256, 0, stream>>>(bcur, pairs, csr_src, rowptr, cnt, dis,
                                     (const float4*)x, (uint2*)xbs, N, NB);

  int rb = (N + 63)/64;
  k_fused1  <<<rb, 512, 0, stream>>>(xbs, rowptr, cnt, csr_src, dis,
                                     wf1, wf2, b1, h1, t2s, N);

  int ab = (N + 3)/4;
  k_aggL2   <<<ab, 256, 0, stream>>>((const unsigned*)t2s, h2, rowptr, cnt,
                                     csr_src, dis, b2, W3, u, N);
  k_agg1d   <<<(N + 15)/16, 256, 0, stream>>>(u, y, rowptr, cnt, csr_src, dis, b3, N);
}

// Round 5
// 242.802 us; speedup vs baseline: 1.3396x; 1.3396x over previous
//
#include <hip/hip_runtime.h>

// GCN3 round 10 (resubmit; round-4 bench failed on container acquisition, not
// kernel). Revert r9's over-fusion (1 block/CU killed the gather).
// Structure = round 8, plus: (a) xscale stays fused into k_place (r9 part
// that worked), (b) NEW k_gemm12 = gemm1+gemm2 in one kernel via a 32KB
// XOR-swizzled LDS h1-tile; weights read direct from L2 (no W staging, so
// LDS stays small -> 2+ blocks/CU). Saves 51.2MB h1 fp32 re-read + 2
// dispatch gaps vs round 8. aggL1/aggL2/agg1d identical to round 8.

typedef __attribute__((ext_vector_type(8))) short short8;   // 8 bf16 (4 VGPR)
typedef __attribute__((ext_vector_type(4))) float f32x4;    // MFMA C/D

static __device__ __forceinline__ unsigned short f2bf(float f){
  union { float f; unsigned u; } v; v.f = f;
  unsigned r = v.u + 0x7FFF + ((v.u >> 16) & 1);            // RNE
  return (unsigned short)(r >> 16);
}
static __device__ __forceinline__ float2 bf2f2(unsigned u){
  union { unsigned u; float f; } a, b;
  a.u = u << 16; b.u = u & 0xffff0000u;
  return make_float2(a.f, b.f);
}

// ---------------- fused: edge binning + W frag-pack ----------------
__global__ __launch_bounds__(256) void k_prepbin(
    const int* __restrict__ src, const int* __restrict__ dst,
    int* __restrict__ bcur, unsigned* __restrict__ pairs, int E, int binB,
    const float* __restrict__ W1, const float* __restrict__ W2,
    unsigned short* __restrict__ Wf1, unsigned short* __restrict__ Wf2){
  __shared__ int cl[256];
  int blk = blockIdx.x;
  int tid = threadIdx.x;
  if (blk < binB){
    int e0 = blk * 4096 + tid;
    cl[tid] = 0; __syncthreads();
    #pragma unroll
    for (int i = 0; i < 16; i++){
      int e = e0 + i*256;
      if (e < E) atomicAdd(&cl[dst[e] >> 8], 1);
    }
    __syncthreads();
    int c = cl[tid];
    int g = (c > 0) ? atomicAdd(&bcur[tid], c) : 0;   // reserve contiguous run
    cl[tid] = g;
    __syncthreads();
    #pragma unroll
    for (int i = 0; i < 16; i++){
      int e = e0 + i*256;
      if (e < E){
        int d = dst[e];
        int b = d >> 8;
        int p = atomicAdd(&cl[b], 1);
        pairs[(b << 13) + p] = (unsigned)src[e] | ((unsigned)(d & 255) << 16);
      }
    }
  } else {
    int t = (blk - binB)*256 + tid;                   // 65536 pack threads
    if (t < 32768){
      // Wf1 [16 nt][4 kt][64 lane][8 j] from W1[128][256]
      int j = t & 7, lane = (t>>3) & 63, kt = (t>>9) & 3, nt = t >> 11;
      int nn = nt*16 + (lane & 15);
      int kk = kt*32 + (lane>>4)*8 + j;
      Wf1[t] = f2bf(W1[kk*256 + nn]);
    } else {
      // Wf2 [2 h][8 kt][4 ntl][64 lane][8 j] from W2[256][128]; nt = h*4+ntl
      int o = t - 32768;
      int j = o & 7, lane = (o>>3) & 63, ntl = (o>>9) & 3, kt = (o>>11) & 7, h = o >> 14;
      int nn = (h*4 + ntl)*16 + (lane & 15);
      int kk = kt*32 + (lane>>4)*8 + j;
      Wf2[o] = f2bf(W2[kk*128 + nn]);
    }
  }
}

// one block per bucket: node histogram + scans -> rowptr/cnt/dis + csr scatter
// + fused x -> bf16 prescale (xbs = bf16(dis*x)) for this block's 256 nodes
__global__ __launch_bounds__(256) void k_place(
    const int* __restrict__ bcur, const unsigned* __restrict__ pairs,
    unsigned short* __restrict__ csr_src, int* __restrict__ rowptr,
    int* __restrict__ cnt, float* __restrict__ dis,
    const float4* __restrict__ x, uint2* __restrict__ xbs,
    int n, int nb){
  __shared__ int sh[256];
  __shared__ int ncnt[256];
  __shared__ float disl[256];
  int t = threadIdx.x;
  int b = blockIdx.x;
  int v = (t < nb) ? bcur[t] : 0;
  sh[t] = v; __syncthreads();
  for (int off = 1; off < 256; off <<= 1){
    int xx = (t >= off) ? sh[t-off] : 0;
    __syncthreads(); sh[t] += xx; __syncthreads();
  }
  int csr_base = (b == 0) ? 0 : sh[b-1];
  int cnt_b = bcur[b];
  ncnt[t] = 0; __syncthreads();
  const unsigned* P = pairs + ((size_t)b << 13);
  for (int i = t; i < cnt_b; i += 256) atomicAdd(&ncnt[P[i] >> 16], 1);
  __syncthreads();
  int c = ncnt[t];
  sh[t] = c; __syncthreads();
  for (int off = 1; off < 256; off <<= 1){
    int xx = (t >= off) ? sh[t-off] : 0;
    __syncthreads(); sh[t] += xx; __syncthreads();
  }
  int noff = sh[t] - c;
  int node = (b << 8) + t;
  float di = rsqrtf((float)(c + 1));
  disl[t] = di;
  if (node < n){
    rowptr[node] = csr_base + noff;
    cnt[node] = c;
    dis[node] = di;                               // +1 self loop
  }
  ncnt[t] = noff; __syncthreads();
  for (int i = t; i < cnt_b; i += 256){
    unsigned u = P[i];
    int p = atomicAdd(&ncnt[u >> 16], 1);
    csr_src[csr_base + p] = (unsigned short)(u & 0xffff);
  }
  // fused xscale: this block's 256 nodes = float4 range [b*8192, b*8192+8192)
  const float4* xg = x + (size_t)b*8192;
  uint2* xo = xbs + (size_t)b*8192;
  int lim = n*32 - b*8192;
  for (int i = t; i < 8192 && i < lim; i += 256){
    float d = disl[i >> 5];
    float4 vv = xg[i];
    xo[i] = make_uint2((unsigned)f2bf(d*vv.x) | ((unsigned)f2bf(d*vv.y) << 16),
                       (unsigned)f2bf(d*vv.z) | ((unsigned)f2bf(d*vv.w) << 16));
  }
}

// ---------------- aggregation L1: prescaled bf16 gather -> xa bf16 ----------------
__global__ void k_aggL1(const unsigned* __restrict__ xbs, unsigned* __restrict__ out,
                        const int* __restrict__ rowptr, const int* __restrict__ cnt,
                        const unsigned short* __restrict__ csr_src,
                        const float* __restrict__ dis, int n){
  int t = threadIdx.x;
  int lane = t & 63;
  int node = blockIdx.x*4 + (t >> 6);
  if (node >= n) return;
  float di = dis[node];
  float2 acc = bf2f2(xbs[(size_t)node*64 + lane]);   // self term (prescaled)
  int start = rowptr[node];
  int mm = cnt[node];
  int j = 0;
  for (; j + 15 < mm; j += 16){
    int s[16]; unsigned uv[16];
    #pragma unroll
    for (int q = 0; q < 16; q++) s[q] = csr_src[start+j+q];
    #pragma unroll
    for (int q = 0; q < 16; q++) uv[q] = xbs[(size_t)s[q]*64 + lane];
    #pragma unroll
    for (int q = 0; q < 16; q++){
      float2 u = bf2f2(uv[q]);
      acc.x += u.x; acc.y += u.y;
    }
  }
  for (; j + 3 < mm; j += 4){
    int s[4]; unsigned uv[4];
    #pragma unroll
    for (int q = 0; q < 4; q++) s[q] = csr_src[start+j+q];
    #pragma unroll
    for (int q = 0; q < 4; q++) uv[q] = xbs[(size_t)s[q]*64 + lane];
    #pragma unroll
    for (int q = 0; q < 4; q++){
      float2 u = bf2f2(uv[q]);
      acc.x += u.x; acc.y += u.y;
    }
  }
  for (; j < mm; j++){
    float2 u = bf2f2(xbs[(size_t)csr_src[start+j]*64 + lane]);
    acc.x += u.x; acc.y += u.y;
  }
  out[(size_t)node*64 + lane] =
      (unsigned)f2bf(di*acc.x) | ((unsigned)f2bf(di*acc.y) << 16);
}

// ---------------- fused GEMM1+GEMM2: xa @ W1 -> h1 (out, fp32) ; bf16(h1) @ W2 -> t2s ----------------
// 64 rows/block, 512 thr, LDS = 32KB swizzled h1 tile. Weights direct from L2.
__global__ __launch_bounds__(512) void k_gemm12(
    const unsigned short* __restrict__ Xa,
    const unsigned short* __restrict__ Wf1, const unsigned short* __restrict__ Wf2,
    const float* __restrict__ b1, const float* __restrict__ dis,
    float* __restrict__ h1, unsigned short* __restrict__ T2s, int n)
{
  __shared__ unsigned short h1l[64*256];    // 32 KB: [64 rows][256 bf16], XOR-swizzled
  int t = threadIdx.x;
  int w = t >> 6, lane = t & 63, m = lane & 15, q = lane >> 4;
  int row0 = blockIdx.x * 64;
  int stripe = w & 3;              // 16-row stripe
  int nth = w >> 2;                // col half
  int rowm = row0 + stripe*16 + m;
  int ra = (rowm < n) ? rowm : (n-1);

  // ---- GEMM1: A direct from global, B direct from L2-hot Wf1 ----
  short8 af[4];
  {
    const short8* Arow = (const short8*)(Xa + (size_t)ra*128);
    #pragma unroll
    for (int kt = 0; kt < 4; kt++) af[kt] = Arow[kt*4 + q];
  }
  f32x4 acc1[8];
  #pragma unroll
  for (int i = 0; i < 8; i++) acc1[i] = (f32x4){0.f,0.f,0.f,0.f};
  const short8* Wv1 = (const short8*)Wf1;
  #pragma unroll
  for (int nt = 0; nt < 8; nt++){
    int ntg = nth*8 + nt;
    #pragma unroll
    for (int kt = 0; kt < 4; kt++){
      short8 bfr = Wv1[(ntg*4 + kt)*64 + lane];
      acc1[nt] = __builtin_amdgcn_mfma_f32_16x16x32_bf16(af[kt], bfr, acc1[nt], 0, 0, 0);
    }
  }
  // store h1 fp32 (required output) + bf16 into swizzled LDS tile
  int rowa = row0 + stripe*16 + q*4;
  int rla  = stripe*16 + q*4;               // block-local row base
  #pragma unroll
  for (int nt = 0; nt < 8; nt++){
    int col = nth*128 + nt*16 + m;
    float b = b1[col];
    #pragma unroll
    for (int r = 0; r < 4; r++){
      int rr = rowa + r;
      float o = fmaxf(acc1[nt][r] + b, 0.0f);
      if (rr < n) h1[(size_t)rr*256 + col] = o;
      int rl = rla + r;
      unsigned byte = (unsigned)(rl*512) + (((unsigned)col*2) ^ ((unsigned)(rl & 7) << 4));
      *(unsigned short*)((char*)h1l + byte) = f2bf(o);
    }
  }
  __syncthreads();

  // ---- GEMM2: A from LDS tile (swizzled), B direct from L2-hot Wf2 ----
  short8 af2[8];
  {
    int rl = stripe*16 + m;
    #pragma unroll
    for (int kt = 0; kt < 8; kt++){
      unsigned byte = (unsigned)(rl*512) + (((unsigned)(kt*64 + q*16)) ^ ((unsigned)(rl & 7) << 4));
      af2[kt] = *(const short8*)((const char*)h1l + byte);
    }
  }
  f32x4 acc2[4];
  #pragma unroll
  for (int i = 0; i < 4; i++) acc2[i] = (f32x4){0.f,0.f,0.f,0.f};
  const short8* Wv2 = (const short8*)Wf2;
  #pragma unroll
  for (int nt = 0; nt < 4; nt++){
    #pragma unroll
    for (int kt = 0; kt < 8; kt++){
      short8 bfr = Wv2[((nth*8 + kt)*4 + nt)*64 + lane];
      acc2[nt] = __builtin_amdgcn_mfma_f32_16x16x32_bf16(af2[kt], bfr, acc2[nt], 0, 0, 0);
    }
  }
  float dsv[4];
  #pragma unroll
  for (int r = 0; r < 4; r++){
    int rr = rowa + r;
    dsv[r] = (rr < n) ? dis[rr] : 0.0f;
  }
  #pragma unroll
  for (int nt = 0; nt < 4; nt++){
    int col = nth*64 + nt*16 + m;
    #pragma unroll
    for (int r = 0; r < 4; r++){
      int rr = rowa + r;
      if (rr < n) T2s[(size_t)rr*128 + col] = f2bf(dsv[r] * acc2[nt][r]);
    }
  }
}

// ---------------- aggregation L2: prescaled gather -> h2 fp32 (+b2,relu) + us=dis*(h2.W3) ----------------
__global__ void k_aggL2(const unsigned* __restrict__ t2s, float* __restrict__ h2,
                        const int* __restrict__ rowptr, const int* __restrict__ cnt,
                        const unsigned short* __restrict__ csr_src,
                        const float* __restrict__ dis,
                        const float* __restrict__ b2, const float* __restrict__ W3,
                        float* __restrict__ u, int n){
  int t = threadIdx.x;
  int lane = t & 63;
  int node = blockIdx.x*4 + (t >> 6);
  if (node >= n) return;
  float di = dis[node];
  float2 acc = bf2f2(t2s[(size_t)node*64 + lane]);   // self term (prescaled)
  int start = rowptr[node];
  int mm = cnt[node];
  int j = 0;
  for (; j + 15 < mm; j += 16){
    int s[16]; unsigned uv[16];
    #pragma unroll
    for (int q = 0; q < 16; q++) s[q] = csr_src[start+j+q];
    #pragma unroll
    for (int q = 0; q < 16; q++) uv[q] = t2s[(size_t)s[q]*64 + lane];
    #pragma unroll
    for (int q = 0; q < 16; q++){
      float2 uu = bf2f2(uv[q]);
      acc.x += uu.x; acc.y += uu.y;
    }
  }
  for (; j + 3 < mm; j += 4){
    int s[4]; unsigned uv[4];
    #pragma unroll
    for (int q = 0; q < 4; q++) s[q] = csr_src[start+j+q];
    #pragma unroll
    for (int q = 0; q < 4; q++) uv[q] = t2s[(size_t)s[q]*64 + lane];
    #pragma unroll
    for (int q = 0; q < 4; q++){
      float2 uu = bf2f2(uv[q]);
      acc.x += uu.x; acc.y += uu.y;
    }
  }
  for (; j < mm; j++){
    float2 uu = bf2f2(t2s[(size_t)csr_src[start+j]*64 + lane]);
    acc.x += uu.x; acc.y += uu.y;
  }
  float2 b = ((const float2*)b2)[lane];
  acc.x = fmaxf(fmaf(di, acc.x, b.x), 0.0f);
  acc.y = fmaxf(fmaf(di, acc.y, b.y), 0.0f);
  ((float2*)h2)[(size_t)node*64 + lane] = acc;
  float up = fmaf(acc.x, W3[2*lane], acc.y * W3[2*lane+1]);
  #pragma unroll
  for (int off = 32; off > 0; off >>= 1) up += __shfl_down(up, off);
  if (lane == 0) u[node] = di * up;               // pre-scaled for final agg
}

// ---------------- final scalar aggregation: 16 lanes per node ----------------
__global__ void k_agg1d(const float* __restrict__ us, float* __restrict__ y,
                        const int* __restrict__ rowptr, const int* __restrict__ cnt,
                        const unsigned short* __restrict__ csr_src,
                        const float* __restrict__ dis,
                        const float* __restrict__ b3, int n){
  int t = threadIdx.x;
  int node = blockIdx.x*16 + (t >> 4);
  int sub = t & 15;
  if (node >= n) return;
  int s0 = rowptr[node];
  int m = cnt[node];
  float acc = (sub == 0) ? us[node] : 0.0f;        // self (prescaled)
  for (int j = sub; j < m; j += 16)
    acc += us[csr_src[s0 + j]];
  #pragma unroll
  for (int off = 8; off > 0; off >>= 1) acc += __shfl_xor(acc, off);
  if (sub == 0) y[node] = fmaf(dis[node], acc, b3[0]);
}

extern "C" void kernel_launch(void* const* d_in, const int* in_sizes, int n_in,
                              void* d_out, int out_size, void* d_ws, size_t ws_size,
                              hipStream_t stream){
  const float* x  = (const float*)d_in[0];
  const int*  ei  = (const int*)d_in[1];
  const float* W1 = (const float*)d_in[2];
  const float* b1 = (const float*)d_in[3];
  const float* W2 = (const float*)d_in[4];
  const float* b2 = (const float*)d_in[5];
  const float* W3 = (const float*)d_in[6];
  const float* b3 = (const float*)d_in[7];
  const int N = in_sizes[0] / 128;
  const int E = in_sizes[1] / 2;
  const int* src = ei;
  const int* dst = ei + E;
  const int NB = (N + 255) >> 8;      // 196 buckets

  char* p = (char*)d_ws;
  auto alloc = [&](size_t bytes)->char*{
    char* r = p; p += (bytes + 255) & ~(size_t)255; return r;
  };
  int*   bcur    = (int*)  alloc(256*4);
  int*   rowptr  = (int*)  alloc((size_t)N*4);
  int*   cnt     = (int*)  alloc((size_t)N*4);
  float* dis     = (float*)alloc((size_t)N*4);
  unsigned* pairs = (unsigned*)alloc((size_t)NB*8192*4);
  unsigned short* csr_src = (unsigned short*)alloc((size_t)E*2);
  unsigned* xbs  = (unsigned*)alloc((size_t)N*128*2);   // bf16 dis*x
  unsigned* xa   = (unsigned*)alloc((size_t)N*128*2);   // bf16 agg(x)
  unsigned short* t2s = (unsigned short*)alloc((size_t)N*128*2); // bf16 dis*(h1@W2)
  float* u       = (float*)alloc((size_t)N*4);          // dis*(h2@W3)
  unsigned short* wf1 = (unsigned short*)alloc(32768*2);
  unsigned short* wf2 = (unsigned short*)alloc(32768*2);

  float* y  = (float*)d_out;
  float* h1 = y + N;
  float* h2 = h1 + (size_t)N*256;

  int bb = (E + 4095)/4096;           // 196 bin blocks

  hipMemsetAsync(bcur, 0, 256*4, stream);
  k_prepbin <<<bb + 256, 256, 0, stream>>>(
      src, dst, bcur, pairs, E, bb, W1, W2, wf1, wf2);
  k_place   <<<NB, 256, 0, stream>>>(bcur, pairs, csr_src, rowptr, cnt, dis,
                                     (const float4*)x, (uint2*)xbs, N, NB);

  int ab = (N + 3)/4;
  int rb = (N + 63)/64;
  k_aggL1   <<<ab, 256, 0, stream>>>(xbs, (unsigned*)xa, rowptr, cnt, csr_src, dis, N);
  k_gemm12  <<<rb, 512, 0, stream>>>((const unsigned short*)xa, wf1, wf2, b1, dis,
                                     h1, t2s, N);
  k_aggL2   <<<ab, 256, 0, stream>>>((const unsigned*)t2s, h2, rowptr, cnt,
                                     csr_src, dis, b2, W3, u, N);
  k_agg1d   <<<(N + 15)/16, 256, 0, stream>>>(u, y, rowptr, cnt, csr_src, dis, b3, N);
}